// Round 12
// baseline (119.424 us; speedup 1.0000x reference)
//
#include <hip/hip_runtime.h>
#include <hip/hip_bf16.h>

typedef unsigned short u16;
typedef unsigned int u32;
typedef __attribute__((ext_vector_type(8))) short s8v;    // 8 bf16 in 4 VGPRs
typedef __attribute__((ext_vector_type(4))) float f4v;    // 16x16 accumulator
typedef __attribute__((ext_vector_type(16))) float f16v;  // 32x32 accumulator

#define B_N 8
#define L_Q 2048
#define L_K 2048
#define DIM 128
#define KT  64
#define KSPLIT 4
#define KCHUNK (L_K / KSPLIT)   // 512 keys per split
#define NIT (KCHUNK / KT)       // 8 iters

__device__ __forceinline__ u16 f2bf(float f) {
  union { float f; unsigned u; } v; v.f = f;
  return (u16)((v.u + 0x7fffu + ((v.u >> 16) & 1u)) >> 16);  // RTN-even
}
__device__ __forceinline__ float bf2f(u16 u) {
  union { u32 u; float f; } v; v.u = ((u32)u) << 16; return v.f;
}
__device__ __forceinline__ u32 packbf2(float a, float b) {   // v_cvt_pk_bf16_f32
  union { __hip_bfloat162 h; u32 u; } v;
  v.h = __float22bfloat162_rn(make_float2(a, b));
  return v.u;
}
__device__ __forceinline__ void async16(const u16* g, u16* l) {
  __builtin_amdgcn_global_load_lds(
      (const __attribute__((address_space(1))) u32*)(const void*)g,
      (__attribute__((address_space(3))) u32*)(void*)l, 16, 0, 0);
}

// ===========================================================================
// 4 dispatches. XCD-locality: ALL kernels map batch b = blockIdx&7 so the
// producer and consumer of qp/kp/vp (proj->flash) and po (flash->combine)
// land on the same XCD's L2 under the bi%8 round-robin dispatch heuristic.
// po frag-linear [p][b][qb][w4][ntv][lane][reg] bf16.
// Softmax: NO online max (scores bounded by Cauchy-Schwarz, exp2 can't
// overflow fp32; shift-invariance => raw exp2 + straight sums).
// ===========================================================================

// ---------------------------------------------------------------------------
// wprep: W -> bf16 16x16-B-frag order (scale*log2e folded into Wq). grid 3.
// ---------------------------------------------------------------------------
__global__ __launch_bounds__(256) void wprep(
    const float* __restrict__ Wq, const float* __restrict__ Wk,
    const float* __restrict__ Wv, u16* __restrict__ wbuf) {
  const int which = blockIdx.x;
  const int tid = threadIdx.x;
  const float* W = (which == 0) ? Wq : (which == 1) ? Wk : Wv;
  const float wscale = (which == 0) ? (1.44269504089f / 11.3137084990f) : 1.0f;
  u16* dst = wbuf + which * 16384;
#pragma unroll
  for (int i = 0; i < 16; ++i) {
    int f4i = tid + i * 256;                 // 4096 float4 chunks of W
    float4 w4 = *(const float4*)(W + f4i * 4);
    int k = f4i >> 5, col = (f4i & 31) * 4;
    int ks = k >> 5, qd = (k & 31) >> 3, j = k & 7;
    float wv4[4] = {w4.x, w4.y, w4.z, w4.w};
#pragma unroll
    for (int c = 0; c < 4; ++c) {
      int n = col + c;
      dst[(ks * 8 + (n >> 4)) * 512 + (qd * 16 + (n & 15)) * 8 + j] = f2bf(wv4[c] * wscale);
    }
  }
}

// ---------------------------------------------------------------------------
// Projections: 16x16x32 MFMA, W-frags DMA'd to LDS once per block.
// grid 768 = which(3) x rt(32) x b(8, low bits -> XCD-local writes).
// ---------------------------------------------------------------------------
__global__ __launch_bounds__(256, 3) void proj_mfma(
    const float* __restrict__ query, const float* __restrict__ key,
    const float* __restrict__ value, const u16* __restrict__ wbuf,
    u16* __restrict__ qp, u16* __restrict__ kp, u16* __restrict__ vp) {
  __shared__ __align__(16) u16 Wf[16384];      // 32KB W-frags
  __shared__ __align__(16) u16 Fb[8192];       // 16KB output staging
  const int tid = threadIdx.x;
  const int bi = blockIdx.x;
  const int which = bi >> 8;           // 0=q 1=k 2=v
  const int sub = bi & 255;
  const int b = sub & 7;               // batch -> XCD (matches flash)
  const int rt = sub >> 3;             // 64-row tile
  const float* X = (which == 0) ? query : (which == 1) ? key : value;
  const u16* Wfg = wbuf + which * 16384;

  const int w = tid >> 6, lane = tid & 63;
  const int ln = lane & 15, quad = lane >> 4;

  // DMA W-frags: 32 chunk-groups of 1KB, wave w does groups w*8..w*8+7
#pragma unroll
  for (int c = 0; c < 8; ++c) {
    int cg = w * 8 + c;
    async16(Wfg + (size_t)(cg * 64 + lane) * 8, Wf + cg * 512);
  }

  const int xrow = rt * 64 + w * 16 + ln;
  const float* Xr = X + ((size_t)b * L_Q + xrow) * DIM;

  s8v a[4];
#pragma unroll
  for (int ks = 0; ks < 4; ++ks) {
    float4 xa = *(const float4*)(Xr + ks * 32 + quad * 8);
    float4 xb = *(const float4*)(Xr + ks * 32 + quad * 8 + 4);
    union { u32 wd[4]; s8v v; } t;
    t.wd[0] = packbf2(xa.x, xa.y);
    t.wd[1] = packbf2(xa.z, xa.w);
    t.wd[2] = packbf2(xb.x, xb.y);
    t.wd[3] = packbf2(xb.z, xb.w);
    a[ks] = t.v;
  }
  __syncthreads();   // W-frags resident

  f4v acc[8];
#pragma unroll
  for (int i = 0; i < 8; ++i) acc[i] = (f4v){0.f, 0.f, 0.f, 0.f};
#pragma unroll
  for (int ks = 0; ks < 4; ++ks)
#pragma unroll
    for (int nt = 0; nt < 8; ++nt) {
      s8v bw = *(const s8v*)(Wf + (ks * 8 + nt) * 512 + lane * 8);
      acc[nt] = __builtin_amdgcn_mfma_f32_16x16x32_bf16(a[ks], bw, acc[nt], 0, 0, 0);
    }

  // C elem: row=w*16+quad*4+r, col=nt*16+ln -> 32x32-frag order staging
  if (which < 2) {
    // frag f=(w>>1)*8+nt ; lane'=(ln>>3)*32+(w&1)*16+quad*4+r ; j=ln&7
#pragma unroll
    for (int nt = 0; nt < 8; ++nt) {
      int base = ((w >> 1) * 8 + nt) * 512 + ((ln >> 3) * 32 + (w & 1) * 16 + quad * 4) * 8 + (ln & 7);
#pragma unroll
      for (int r = 0; r < 4; ++r) Fb[base + r * 8] = f2bf(acc[nt][r]);
    }
  } else {
    // frag f=w*4+(nt>>1) ; lane'=(quad>>1)*32+(nt&1)*16+ln ; j=(quad&1)*4+r
#pragma unroll
    for (int nt = 0; nt < 8; ++nt) {
      int base = (w * 4 + (nt >> 1)) * 512 + ((quad >> 1) * 32 + (nt & 1) * 16 + ln) * 8 + (quad & 1) * 4;
      *(u32*)&Fb[base]     = packbf2(acc[nt][0], acc[nt][1]);
      *(u32*)&Fb[base + 2] = packbf2(acc[nt][2], acc[nt][3]);
    }
  }
  __syncthreads();

  u16* Y = ((which == 0) ? qp : (which == 1) ? kp : vp) + (size_t)(b * 32 + rt) * 8192;
#pragma unroll
  for (int r = 0; r < 4; ++r) {
    int c = tid + r * 256;                 // 1024 16B chunks, identity copy
    *(s8v*)(Y + c * 8) = *(const s8v*)(Fb + c * 8);
  }
}

// ---------------------------------------------------------------------------
// K-split flash, 32x32x16 MFMA, S^T formulation, NO online max,
// shuffle-based P transform, double-buffered pipelined K/V staging.
// grid 512 = b(8, ->XCD) x part(4) x qb(16 of 128 rows); block 256.
// LDS 66,560B -> 2 blocks/CU (grid == exactly 2/CU resident).
// ---------------------------------------------------------------------------
__global__ __launch_bounds__(256, 2) void flash_split(
    const u16* __restrict__ qp, const u16* __restrict__ kp,
    const u16* __restrict__ vp, const int* __restrict__ mask,
    u16* __restrict__ po, float* __restrict__ lbuf) {
  __shared__ __align__(16) u16 Kf[2][8192];   // 2 x 16 frags x 1KB
  __shared__ __align__(16) u16 Vf[2][8192];
  __shared__ float biasl[2][KT];

  const int tid = threadIdx.x;
  const int bi = blockIdx.x;
  const int b = bi & 7;               // batch -> XCD
  const int rest = bi >> 3;
  const int p = rest & 3;
  const int qb = rest >> 2;           // 0..15 (128 q-rows)
  const int w4 = tid >> 6;
  const int lane = tid & 63;
  const int qcol = lane & 31;
  const int H = lane >> 5;
  const bool Hb = (H != 0);

  const int* mb = mask + b * L_K;
  const int kt0 = p * NIT;

  auto stage = [&](int bufi, int kt_) {
    const u16* Ktile = kp + (size_t)(b * 32 + kt_) * 8192;
    const u16* Vtile = vp + (size_t)(b * 32 + kt_) * 8192;
#pragma unroll
    for (int c = 0; c < 4; ++c) {
      int f = w4 * 4 + c;
      async16(Ktile + (size_t)(f * 64 + lane) * 8, &Kf[bufi][f * 512]);
      async16(Vtile + (size_t)(f * 64 + lane) * 8, &Vf[bufi][f * 512]);
    }
  };

  // Q fragments for this wave's 32 rows (tile qb*4 + w4), resident
  const u16* Qt = qp + (size_t)(b * 64 + qb * 4 + w4) * 4096;
  s8v aq[8];
#pragma unroll
  for (int c = 0; c < 8; ++c) aq[c] = *(const s8v*)(Qt + c * 512 + lane * 8);

  f16v o[4];
#pragma unroll
  for (int i = 0; i < 4; ++i)
#pragma unroll
    for (int r = 0; r < 16; ++r) o[i][r] = 0.f;
  float lrow = 0.f;

  // prologue: stage tile 0 + its mask bias
  stage(0, kt0);
  int mv0 = mb[kt0 * KT + lane];
  bool ao_next = (__ballot(mv0 != 0) == ~0ull);
  if (!ao_next && tid < KT) biasl[0][tid] = (mv0 == 0) ? -__builtin_inff() : 0.f;
  __syncthreads();

  for (int it = 0; it < NIT; ++it) {
    const int cur = it & 1;
    const bool allones = ao_next;

    // pipeline: issue next tile's staging NOW; end-of-iter barrier drains it
    if (it + 1 < NIT) {
      stage(cur ^ 1, kt0 + it + 1);
      int mv = mb[(kt0 + it + 1) * KT + lane];
      ao_next = (__ballot(mv != 0) == ~0ull);
      if (!ao_next && tid < KT) biasl[cur ^ 1][tid] = (mv == 0) ? -__builtin_inff() : 0.f;
    }

    // S^T = K Q^T: s[t] covers keys t*32..+32 (rows), q = col = lane&31
    f16v s[2];
#pragma unroll
    for (int t = 0; t < 2; ++t)
#pragma unroll
      for (int r = 0; r < 16; ++r) s[t][r] = 0.f;
#pragma unroll
    for (int c = 0; c < 8; ++c) {
      s8v k0f = *(const s8v*)(&Kf[cur][c * 512] + lane * 8);
      s[0] = __builtin_amdgcn_mfma_f32_32x32x16_bf16(k0f, aq[c], s[0], 0, 0, 0);
      s8v k1f = *(const s8v*)(&Kf[cur][(8 + c) * 512] + lane * 8);
      s[1] = __builtin_amdgcn_mfma_f32_32x32x16_bf16(k1f, aq[c], s[1], 0, 0, 0);
    }
    if (!allones) {
#pragma unroll
      for (int t = 0; t < 2; ++t)
#pragma unroll
        for (int g = 0; g < 4; ++g) {
          float4 bt = *(const float4*)&biasl[cur][t * 32 + g * 8 + 4 * H];
          s[t][g * 4 + 0] += bt.x; s[t][g * 4 + 1] += bt.y;
          s[t][g * 4 + 2] += bt.z; s[t][g * 4 + 3] += bt.w;
        }
    }

    // p = exp2(s) raw (no max subtraction — cannot overflow)
    float rs = 0.f;
#pragma unroll
    for (int t = 0; t < 2; ++t)
#pragma unroll
      for (int r = 0; r < 16; ++r) {
        s[t][r] = __builtin_amdgcn_exp2f(s[t][r]);
        rs += s[t][r];
      }
    rs += __shfl_xor(rs, 32, 64);
    lrow += rs;

    // pack P pairs: (t,g) -> keys t*32+8g+4H+{0..3}
    u32 plo[2][4], phi[2][4];
#pragma unroll
    for (int t = 0; t < 2; ++t)
#pragma unroll
      for (int g = 0; g < 4; ++g) {
        plo[t][g] = packbf2(s[t][g * 4 + 0], s[t][g * 4 + 1]);
        phi[t][g] = packbf2(s[t][g * 4 + 2], s[t][g * 4 + 3]);
      }

    // O += P V. A-frag(kc): keys kc*16+8H+{0..7}; partner-half exchange.
#pragma unroll
    for (int kc = 0; kc < 4; ++kc) {
      const int t = kc >> 1, gl = (kc & 1) * 2;
      u32 a_lo0 = plo[t][gl], a_hi0 = phi[t][gl];
      u32 a_lo1 = plo[t][gl + 1], a_hi1 = phi[t][gl + 1];
      u32 snd_lo = Hb ? a_lo0 : a_lo1;
      u32 snd_hi = Hb ? a_hi0 : a_hi1;
      u32 r_lo = (u32)__shfl_xor((int)snd_lo, 32, 64);
      u32 r_hi = (u32)__shfl_xor((int)snd_hi, 32, 64);
      union { u32 wd[4]; s8v v; } pa;
      pa.wd[0] = Hb ? r_lo : a_lo0;
      pa.wd[1] = Hb ? r_hi : a_hi0;
      pa.wd[2] = Hb ? a_lo1 : r_lo;
      pa.wd[3] = Hb ? a_hi1 : r_hi;
#pragma unroll
      for (int ntv = 0; ntv < 4; ++ntv) {
        s8v bv = *(const s8v*)(&Vf[cur][(kc * 4 + ntv) * 512] + lane * 8);
        o[ntv] = __builtin_amdgcn_mfma_f32_32x32x16_bf16(pa.v, bv, o[ntv], 0, 0, 0);
      }
    }
    __syncthreads();   // drains next-tile DMA + seals buffer reuse
  }

  // epilogue: po frag-linear [p][b][qb][w4][ntv][lane][reg] bf16, 32B/lane
  const size_t gidx = ((size_t)((p * 8 + b) * 16 + qb) * 4 + w4);
  u16* pw = po + gidx * 4096 + (size_t)lane * 16;
#pragma unroll
  for (int ntv = 0; ntv < 4; ++ntv) {
    union { u32 wd[4]; s8v v; } h1, h2;
#pragma unroll
    for (int j = 0; j < 4; ++j) {
      h1.wd[j] = packbf2(o[ntv][2 * j], o[ntv][2 * j + 1]);
      h2.wd[j] = packbf2(o[ntv][8 + 2 * j], o[ntv][9 + 2 * j]);
    }
    *(s8v*)(pw + ntv * 1024) = h1.v;
    *(s8v*)(pw + ntv * 1024 + 8) = h2.v;
  }
  if (H == 0) lbuf[gidx * 32 + qcol] = lrow;
}

// ---------------------------------------------------------------------------
// Combine: out[q] = (sum_p O_p) / (sum_p l_p). grid 512 = w4(4) x qb(16) x
// b(8, low bits -> same XCD as flash writers of po). block 256 (wave = ntv).
// ---------------------------------------------------------------------------
__global__ __launch_bounds__(256) void combine(
    const u16* __restrict__ po, const float* __restrict__ lbuf,
    float* __restrict__ out) {
  __shared__ float shL[32];
  const int tid = threadIdx.x;
  const int bi = blockIdx.x;
  const int b = bi & 7;               // batch -> XCD (matches flash)
  const int qb = (bi >> 3) & 15;
  const int w4 = bi >> 7;
  const int wv = tid >> 6;            // = ntv
  const int lane = tid & 63;
  const int qcol = lane & 31;
  const int H = lane >> 5;

  float acc[16];
#pragma unroll
  for (int r = 0; r < 16; ++r) acc[r] = 0.f;
#pragma unroll
  for (int p = 0; p < KSPLIT; ++p) {
    const u16* src = po + ((size_t)((p * 8 + b) * 16 + qb) * 4 + w4) * 4096 + (size_t)(wv * 64 + lane) * 16;
    s8v v1 = *(const s8v*)src;
    s8v v2 = *(const s8v*)(src + 8);
#pragma unroll
    for (int r = 0; r < 8; ++r) {
      acc[r] += bf2f((u16)v1[r]);
      acc[8 + r] += bf2f((u16)v2[r]);
    }
  }
  if (tid < 32) {
    float L = 0.f;
#pragma unroll
    for (int p = 0; p < KSPLIT; ++p)
      L += lbuf[((size_t)((p * 8 + b) * 16 + qb) * 4 + w4) * 32 + tid];
    shL[tid] = 1.0f / L;
  }
  __syncthreads();
#pragma unroll
  for (int reg = 0; reg < 16; ++reg) {
    int qloc = (reg & 3) + 8 * (reg >> 2) + 4 * H;
    size_t q = (size_t)b * L_Q + qb * 128 + w4 * 32 + qloc;
    out[q * DIM + wv * 32 + qcol] = acc[reg] * shL[qloc];
  }
}

extern "C" void kernel_launch(void* const* d_in, const int* in_sizes, int n_in,
                              void* d_out, int out_size, void* d_ws, size_t ws_size,
                              hipStream_t stream) {
  const float* query = (const float*)d_in[0];
  const float* key   = (const float*)d_in[1];
  const float* value = (const float*)d_in[2];
  const float* Wq    = (const float*)d_in[3];
  const float* Wk    = (const float*)d_in[4];
  const float* Wv    = (const float*)d_in[5];
  const int*   mask  = (const int*)d_in[6];
  float* out = (float*)d_out;

  u16* qp = (u16*)d_ws;                                   // 4 MB
  u16* kp = qp + (size_t)B_N * L_Q * DIM;                 // 4 MB
  u16* vp = kp + (size_t)B_N * L_K * DIM;                 // 4 MB
  u16* po = vp + (size_t)B_N * DIM * L_K;                 // 16.8 MB (bf16)
  float* lbuf = (float*)(po + (size_t)B_N * L_Q * KSPLIT * DIM);  // 256 KB
  u16* wbuf = (u16*)(lbuf + (size_t)B_N * L_Q * KSPLIT);          // 96 KB

  hipLaunchKernelGGL(wprep, dim3(3), dim3(256), 0, stream, Wq, Wk, Wv, wbuf);
  hipLaunchKernelGGL(proj_mfma, dim3(768), dim3(256), 0, stream,
                     query, key, value, wbuf, qp, kp, vp);
  hipLaunchKernelGGL(flash_split, dim3(512), dim3(256), 0, stream,
                     qp, kp, vp, mask, po, lbuf);
  hipLaunchKernelGGL(combine, dim3(512), dim3(256), 0, stream,
                     po, lbuf, out);
}

// Round 13
// 115.502 us; speedup vs baseline: 1.0340x; 1.0340x over previous
//
#include <hip/hip_runtime.h>
#include <hip/hip_bf16.h>
#include <hip/hip_cooperative_groups.h>

namespace cg = cooperative_groups;

typedef unsigned short u16;
typedef unsigned int u32;
typedef __attribute__((ext_vector_type(8))) short s8v;    // 8 bf16 in 4 VGPRs
typedef __attribute__((ext_vector_type(4))) float f4v;    // 16x16 accumulator
typedef __attribute__((ext_vector_type(16))) float f16v;  // 32x32 accumulator

#define B_N 8
#define L_Q 2048
#define L_K 2048
#define DIM 128
#define KSPLIT 4
#define NHALF 16   // 32-key half-tiles per split (512 keys)

__device__ __forceinline__ u16 f2bf(float f) {
  union { float f; unsigned u; } v; v.f = f;
  return (u16)((v.u + 0x7fffu + ((v.u >> 16) & 1u)) >> 16);  // RTN-even
}
__device__ __forceinline__ float bf2f(u16 u) {
  union { u32 u; float f; } v; v.u = ((u32)u) << 16; return v.f;
}
__device__ __forceinline__ u32 packbf2(float a, float b) {   // v_cvt_pk_bf16_f32
  union { __hip_bfloat162 h; u32 u; } v;
  v.h = __float22bfloat162_rn(make_float2(a, b));
  return v.u;
}
__device__ __forceinline__ void async16(const u16* g, u16* l) {
  __builtin_amdgcn_global_load_lds(
      (const __attribute__((address_space(1))) u32*)(const void*)g,
      (__attribute__((address_space(3))) u32*)(void*)l, 16, 0, 0);
}

// ===========================================================================
// Phases as __device__ functions shared by (a) one cooperative fused kernel
// (grid 512 x 256, total static LDS 32KB -> 2 blocks/CU under even the most
// pessimistic 64KB-usable occupancy model) and (b) a 4-dispatch fallback.
// Softmax: NO online max (scores bounded by Cauchy-Schwarz; exp2 can't
// overflow fp32; shift-invariance => raw exp2 + straight sums in combine).
// Flash: KT=32 half-tiles, double-buffered (4 x 8KB LDS), S^T formulation,
// shuffle-based P transform. Mask bias: ballot fast path (all-ones), rare
// path reads mask per-register from global.
// po frag-linear [p][b][qb][w4][ntv][lane][reg] bf16.
// ===========================================================================

__device__ __forceinline__ void wprep_dev(
    int g, const float* __restrict__ Wq, const float* __restrict__ Wk,
    const float* __restrict__ Wv, u16* __restrict__ wbuf) {
  if (g >= 3 * 4096) return;
  int which = g >> 12, f4i = g & 4095;
  const float* W = (which == 0) ? Wq : (which == 1) ? Wk : Wv;
  const float wscale = (which == 0) ? (1.44269504089f / 11.3137084990f) : 1.0f;
  u16* dst = wbuf + which * 16384;
  float4 w4 = *(const float4*)(W + f4i * 4);
  int k = f4i >> 5, col = (f4i & 31) * 4;
  int ks = k >> 5, qd = (k & 31) >> 3, j = k & 7;
  float wv4[4] = {w4.x, w4.y, w4.z, w4.w};
#pragma unroll
  for (int c = 0; c < 4; ++c) {
    int n = col + c;
    dst[(ks * 8 + (n >> 4)) * 512 + (qd * 16 + (n & 15)) * 8 + j] = f2bf(wv4[c] * wscale);
  }
}

// proj tile t in [0,768): which = t>>8, sub = t&255, b = sub&7, rt = sub>>3.
// shm: 32KB W-frags. Direct frag-order global stores (no staging buffer).
__device__ __forceinline__ void proj_dev(
    int t, int tid, u16* shm, const float* __restrict__ query,
    const float* __restrict__ key, const float* __restrict__ value,
    const u16* __restrict__ wbuf, u16* __restrict__ qp, u16* __restrict__ kp,
    u16* __restrict__ vp) {
  const int which = t >> 8;
  const int sub = t & 255;
  const int b = sub & 7;
  const int rt = sub >> 3;
  const float* X = (which == 0) ? query : (which == 1) ? key : value;
  const u16* Wfg = wbuf + which * 16384;
  const int w = tid >> 6, lane = tid & 63;
  const int ln = lane & 15, quad = lane >> 4;

#pragma unroll
  for (int c = 0; c < 8; ++c) {
    int cg_ = w * 8 + c;
    async16(Wfg + (size_t)(cg_ * 64 + lane) * 8, shm + cg_ * 512);
  }

  const int xrow = rt * 64 + w * 16 + ln;
  const float* Xr = X + ((size_t)b * L_Q + xrow) * DIM;
  s8v a[4];
#pragma unroll
  for (int ks = 0; ks < 4; ++ks) {
    float4 xa = *(const float4*)(Xr + ks * 32 + quad * 8);
    float4 xb = *(const float4*)(Xr + ks * 32 + quad * 8 + 4);
    union { u32 wd[4]; s8v v; } tt;
    tt.wd[0] = packbf2(xa.x, xa.y);
    tt.wd[1] = packbf2(xa.z, xa.w);
    tt.wd[2] = packbf2(xb.x, xb.y);
    tt.wd[3] = packbf2(xb.z, xb.w);
    a[ks] = tt.v;
  }
  __syncthreads();   // W-frags resident (drains DMA)

  f4v acc[8];
#pragma unroll
  for (int i = 0; i < 8; ++i) acc[i] = (f4v){0.f, 0.f, 0.f, 0.f};
#pragma unroll
  for (int ks = 0; ks < 4; ++ks)
#pragma unroll
    for (int nt = 0; nt < 8; ++nt) {
      s8v bw = *(const s8v*)(shm + (ks * 8 + nt) * 512 + lane * 8);
      acc[nt] = __builtin_amdgcn_mfma_f32_16x16x32_bf16(a[ks], bw, acc[nt], 0, 0, 0);
    }

  // C elem row=w*16+quad*4+r, col=nt*16+ln -> 32x32-frag order, direct stores
  u16* Y = ((which == 0) ? qp : (which == 1) ? kp : vp) + (size_t)(b * 32 + rt) * 8192;
  if (which < 2) {
#pragma unroll
    for (int nt = 0; nt < 8; ++nt) {
      int base = ((w >> 1) * 8 + nt) * 512 + ((ln >> 3) * 32 + (w & 1) * 16 + quad * 4) * 8 + (ln & 7);
#pragma unroll
      for (int r = 0; r < 4; ++r) Y[base + r * 8] = f2bf(acc[nt][r]);
    }
  } else {
#pragma unroll
    for (int nt = 0; nt < 8; ++nt) {
      int base = (w * 4 + (nt >> 1)) * 512 + ((quad >> 1) * 32 + (nt & 1) * 16 + ln) * 8 + (quad & 1) * 4;
      *(u32*)&Y[base]     = packbf2(acc[nt][0], acc[nt][1]);
      *(u32*)&Y[base + 2] = packbf2(acc[nt][2], acc[nt][3]);
    }
  }
  __syncthreads();   // seal shm before a possible next proj iteration
}

// flash block bi in [0,512): b=bi&7, p=(bi>>3)&3, qb=bi>>5.
// shm map (u16): K0 @0, K1 @4096, V0 @8192, V1 @12288  (4 x 8KB).
__device__ __forceinline__ void flash_dev(
    int bi, int tid, u16* shm, const u16* __restrict__ qp,
    const u16* __restrict__ kp, const u16* __restrict__ vp,
    const int* __restrict__ mask, u16* __restrict__ po,
    float* __restrict__ lbuf) {
  const int b = bi & 7;
  const int rest = bi >> 3;
  const int p = rest & 3;
  const int qb = rest >> 2;           // 0..15 (128 q-rows)
  const int w4 = tid >> 6;
  const int lane = tid & 63;
  const int qcol = lane & 31;
  const int H = lane >> 5;
  const bool Hb = (H != 0);
  const int* mb = mask + b * L_K;
  const int hm0 = p * NHALF;

  // Q fragments for this wave's 32 rows, resident
  const u16* Qt = qp + (size_t)(b * 64 + qb * 4 + w4) * 4096;
  s8v aq[8];
#pragma unroll
  for (int c = 0; c < 8; ++c) aq[c] = *(const s8v*)(Qt + c * 512 + lane * 8);

  f16v o[4];
#pragma unroll
  for (int i = 0; i < 4; ++i)
#pragma unroll
    for (int r = 0; r < 16; ++r) o[i][r] = 0.f;
  float lrow = 0.f;

  auto stage = [&](int bufi, int hm) {
    const size_t off = (size_t)(b * 32 + (hm >> 1)) * 8192 + (hm & 1) * 4096;
    if (w4 < 2) {
#pragma unroll
      for (int c = 0; c < 4; ++c) {
        int f = w4 * 4 + c;
        async16(kp + off + (size_t)(f * 64 + lane) * 8, shm + bufi * 4096 + f * 512);
      }
    } else {
#pragma unroll
      for (int c = 0; c < 4; ++c) {
        int f = (w4 - 2) * 4 + c;
        async16(vp + off + (size_t)(f * 64 + lane) * 8, shm + 8192 + bufi * 4096 + f * 512);
      }
    }
  };

  stage(0, hm0);
  int mv0 = mb[hm0 * 32 + (tid & 31)];
  bool ao_next = (__ballot(mv0 != 0) == ~0ull);
  __syncthreads();

  for (int it = 0; it < NHALF; ++it) {
    const int cur = it & 1;
    const bool allones = ao_next;
    const int k0 = (hm0 + it) * 32;
    const u16* Kb = shm + cur * 4096;
    const u16* Vb = shm + 8192 + cur * 4096;

    if (it + 1 < NHALF) {
      stage(cur ^ 1, hm0 + it + 1);
      int mv = mb[(hm0 + it + 1) * 32 + (tid & 31)];
      ao_next = (__ballot(mv != 0) == ~0ull);
    }

    // S^T = K Q^T over 32 keys; q = col = lane&31
    f16v s;
#pragma unroll
    for (int r = 0; r < 16; ++r) s[r] = 0.f;
#pragma unroll
    for (int c = 0; c < 8; ++c) {
      s8v bk = *(const s8v*)(Kb + c * 512 + lane * 8);
      s = __builtin_amdgcn_mfma_f32_32x32x16_bf16(bk, aq[c], s, 0, 0, 0);
    }
    if (!allones) {   // rare path: per-register mask from global
#pragma unroll
      for (int g = 0; g < 4; ++g)
#pragma unroll
        for (int i = 0; i < 4; ++i)
          if (mb[k0 + g * 8 + 4 * H + i] == 0) s[g * 4 + i] = -__builtin_inff();
    }

    // p = exp2(s) raw
    float rs = 0.f;
#pragma unroll
    for (int r = 0; r < 16; ++r) {
      s[r] = __builtin_amdgcn_exp2f(s[r]);
      rs += s[r];
    }
    rs += __shfl_xor(rs, 32, 64);
    lrow += rs;

    // pack P pairs: group g -> keys k0 + g*8 + 4H + {0..3}
    u32 plo[4], phi[4];
#pragma unroll
    for (int g = 0; g < 4; ++g) {
      plo[g] = packbf2(s[g * 4 + 0], s[g * 4 + 1]);
      phi[g] = packbf2(s[g * 4 + 2], s[g * 4 + 3]);
    }

    // O += P V. A-frag(kc): keys kc*16+8H+{0..7}; partner-half exchange.
#pragma unroll
    for (int kc = 0; kc < 2; ++kc) {
      const int gl = kc * 2;
      u32 a_lo0 = plo[gl], a_hi0 = phi[gl];
      u32 a_lo1 = plo[gl + 1], a_hi1 = phi[gl + 1];
      u32 snd_lo = Hb ? a_lo0 : a_lo1;
      u32 snd_hi = Hb ? a_hi0 : a_hi1;
      u32 r_lo = (u32)__shfl_xor((int)snd_lo, 32, 64);
      u32 r_hi = (u32)__shfl_xor((int)snd_hi, 32, 64);
      union { u32 wd[4]; s8v v; } pa;
      pa.wd[0] = Hb ? r_lo : a_lo0;
      pa.wd[1] = Hb ? r_hi : a_hi0;
      pa.wd[2] = Hb ? a_lo1 : r_lo;
      pa.wd[3] = Hb ? a_hi1 : r_hi;
#pragma unroll
      for (int ntv = 0; ntv < 4; ++ntv) {
        s8v bv = *(const s8v*)(Vb + (kc * 4 + ntv) * 512 + lane * 8);
        o[ntv] = __builtin_amdgcn_mfma_f32_32x32x16_bf16(pa.v, bv, o[ntv], 0, 0, 0);
      }
    }
    __syncthreads();   // drains next-tile DMA + seals buffer reuse
  }

  // epilogue: po frag-linear [p][b][qb][w4][ntv][lane][reg] bf16, 32B/lane
  const size_t gidx = ((size_t)((p * 8 + b) * 16 + qb) * 4 + w4);
  u16* pw = po + gidx * 4096 + (size_t)lane * 16;
#pragma unroll
  for (int ntv = 0; ntv < 4; ++ntv) {
    union { u32 wd[4]; s8v v; } h1, h2;
#pragma unroll
    for (int j = 0; j < 4; ++j) {
      h1.wd[j] = packbf2(o[ntv][2 * j], o[ntv][2 * j + 1]);
      h2.wd[j] = packbf2(o[ntv][8 + 2 * j], o[ntv][9 + 2 * j]);
    }
    *(s8v*)(pw + ntv * 1024) = h1.v;
    *(s8v*)(pw + ntv * 1024 + 8) = h2.v;
  }
  if (H == 0) lbuf[gidx * 32 + qcol] = lrow;
}

// combine block bi in [0,512): b=bi&7, qb=(bi>>3)&15, w4=bi>>7.
__device__ __forceinline__ void combine_dev(
    int bi, int tid, u16* shm, const u16* __restrict__ po,
    const float* __restrict__ lbuf, float* __restrict__ out) {
  float* shL = (float*)shm;
  const int b = bi & 7;
  const int qb = (bi >> 3) & 15;
  const int w4 = bi >> 7;
  const int wv = tid >> 6;            // = ntv
  const int lane = tid & 63;
  const int qcol = lane & 31;
  const int H = lane >> 5;

  float acc[16];
#pragma unroll
  for (int r = 0; r < 16; ++r) acc[r] = 0.f;
#pragma unroll
  for (int p = 0; p < KSPLIT; ++p) {
    const u16* src = po + ((size_t)((p * 8 + b) * 16 + qb) * 4 + w4) * 4096 + (size_t)(wv * 64 + lane) * 16;
    s8v v1 = *(const s8v*)src;
    s8v v2 = *(const s8v*)(src + 8);
#pragma unroll
    for (int r = 0; r < 8; ++r) {
      acc[r] += bf2f((u16)v1[r]);
      acc[8 + r] += bf2f((u16)v2[r]);
    }
  }
  if (tid < 32) {
    float L = 0.f;
#pragma unroll
    for (int p = 0; p < KSPLIT; ++p)
      L += lbuf[((size_t)((p * 8 + b) * 16 + qb) * 4 + w4) * 32 + tid];
    shL[tid] = 1.0f / L;
  }
  __syncthreads();
#pragma unroll
  for (int reg = 0; reg < 16; ++reg) {
    int qloc = (reg & 3) + 8 * (reg >> 2) + 4 * H;
    size_t q = (size_t)b * L_Q + qb * 128 + w4 * 32 + qloc;
    out[q * DIM + wv * 32 + qcol] = acc[reg] * shL[qloc];
  }
}

// ---------------------------------------------------------------------------
// Cooperative fused kernel: 32KB static LDS, grid 512 x 256.
// ---------------------------------------------------------------------------
__global__ __launch_bounds__(256, 2) void fused(
    const float* __restrict__ query, const float* __restrict__ key,
    const float* __restrict__ value, const float* __restrict__ Wq,
    const float* __restrict__ Wk, const float* __restrict__ Wv,
    const int* __restrict__ mask, u16* __restrict__ qp, u16* __restrict__ kp,
    u16* __restrict__ vp, u16* __restrict__ wbuf, u16* __restrict__ po,
    float* __restrict__ lbuf, float* __restrict__ out) {
  __shared__ __align__(16) u16 shm[16384];   // 32KB
  cg::grid_group grid = cg::this_grid();
  const int tid = threadIdx.x;
  const int bi = blockIdx.x;

  wprep_dev(bi * 256 + tid, Wq, Wk, Wv, wbuf);
  grid.sync();
  for (int t = bi; t < 768; t += 512)
    proj_dev(t, tid, shm, query, key, value, wbuf, qp, kp, vp);
  grid.sync();
  flash_dev(bi, tid, shm, qp, kp, vp, mask, po, lbuf);
  grid.sync();
  combine_dev(bi, tid, shm, po, lbuf, out);
}

// ---------------------------------------------------------------------------
// Fallback kernels (4 dispatches), same device functions.
// ---------------------------------------------------------------------------
__global__ __launch_bounds__(256) void wprep_k(
    const float* __restrict__ Wq, const float* __restrict__ Wk,
    const float* __restrict__ Wv, u16* __restrict__ wbuf) {
  wprep_dev(blockIdx.x * 256 + threadIdx.x, Wq, Wk, Wv, wbuf);
}
__global__ __launch_bounds__(256, 3) void proj_k(
    const float* __restrict__ query, const float* __restrict__ key,
    const float* __restrict__ value, const u16* __restrict__ wbuf,
    u16* __restrict__ qp, u16* __restrict__ kp, u16* __restrict__ vp) {
  __shared__ __align__(16) u16 shm[16384];
  proj_dev(blockIdx.x, threadIdx.x, shm, query, key, value, wbuf, qp, kp, vp);
}
__global__ __launch_bounds__(256, 2) void flash_k(
    const u16* __restrict__ qp, const u16* __restrict__ kp,
    const u16* __restrict__ vp, const int* __restrict__ mask,
    u16* __restrict__ po, float* __restrict__ lbuf) {
  __shared__ __align__(16) u16 shm[16384];
  flash_dev(blockIdx.x, threadIdx.x, shm, qp, kp, vp, mask, po, lbuf);
}
__global__ __launch_bounds__(256) void combine_k(
    const u16* __restrict__ po, const float* __restrict__ lbuf,
    float* __restrict__ out) {
  __shared__ __align__(16) u16 shm[64];
  combine_dev(blockIdx.x, threadIdx.x, shm, po, lbuf, out);
}

extern "C" void kernel_launch(void* const* d_in, const int* in_sizes, int n_in,
                              void* d_out, int out_size, void* d_ws, size_t ws_size,
                              hipStream_t stream) {
  const float* query = (const float*)d_in[0];
  const float* key   = (const float*)d_in[1];
  const float* value = (const float*)d_in[2];
  const float* Wq    = (const float*)d_in[3];
  const float* Wk    = (const float*)d_in[4];
  const float* Wv    = (const float*)d_in[5];
  const int*   mask  = (const int*)d_in[6];
  float* out = (float*)d_out;

  u16* qp = (u16*)d_ws;                                   // 4 MB
  u16* kp = qp + (size_t)B_N * L_Q * DIM;                 // 4 MB
  u16* vp = kp + (size_t)B_N * L_K * DIM;                 // 4 MB
  u16* po = vp + (size_t)B_N * DIM * L_K;                 // 16.8 MB (bf16)
  float* lbuf = (float*)(po + (size_t)B_N * L_Q * KSPLIT * DIM);  // 256 KB
  u16* wbuf = (u16*)(lbuf + (size_t)B_N * L_Q * KSPLIT);          // 96 KB

  // Deterministic coop-viability check (no stream ops; same result per call).
  int nb = 0;
  hipError_t oe = hipOccupancyMaxActiveBlocksPerMultiprocessor(
      &nb, (const void*)fused, 256, 0);
  if (oe == hipSuccess && nb >= 2) {
    void* args[] = {(void*)&query, (void*)&key, (void*)&value, (void*)&Wq,
                    (void*)&Wk,    (void*)&Wv,  (void*)&mask,  (void*)&qp,
                    (void*)&kp,    (void*)&vp,  (void*)&wbuf,  (void*)&po,
                    (void*)&lbuf,  (void*)&out};
    hipError_t le = hipLaunchCooperativeKernel((void*)fused, dim3(512),
                                               dim3(256), args, 0, stream);
    if (le == hipSuccess) return;
  }

  // Fallback: 4 dispatches
  hipLaunchKernelGGL(wprep_k, dim3(48), dim3(256), 0, stream, Wq, Wk, Wv, wbuf);
  hipLaunchKernelGGL(proj_k, dim3(768), dim3(256), 0, stream,
                     query, key, value, wbuf, qp, kp, vp);
  hipLaunchKernelGGL(flash_k, dim3(512), dim3(256), 0, stream,
                     qp, kp, vp, mask, po, lbuf);
  hipLaunchKernelGGL(combine_k, dim3(512), dim3(256), 0, stream,
                     po, lbuf, out);
}